// Round 1
// baseline (146.039 us; speedup 1.0000x reference)
//
#include <hip/hip_runtime.h>
#include <hip/hip_bf16.h>

// CorrelationNetwork fused kernel for MI355X (gfx950).
// Strategy: precompute Ai (+b1 folded) and Aj in fp32 (tiny GEMM), then one
// fused kernel per 128-row tile of the big (524288 x 128 x 128) h1@W2 GEMM:
// build h1 tile in LDS as bf16 on the fly, MFMA 16x16x32 against W2^T (bf16),
// epilogue relu+dot(w3)+sigmoid in registers. h1/h2 never touch HBM.

typedef __bf16 bf16x8 __attribute__((ext_vector_type(8)));
typedef float f32x4 __attribute__((ext_vector_type(4)));

#define B_SZ 128
#define N_SZ 64
#define H_SZ 128

__device__ __forceinline__ unsigned pack_bf16x2(float lo, float hi) {
  unsigned a = __float_as_uint(lo);
  unsigned b = __float_as_uint(hi);
  a += 0x7fffu + ((a >> 16) & 1u);   // RNE round to bf16
  b += 0x7fffu + ((b >> 16) & 1u);
  return (a >> 16) | (b & 0xffff0000u);
}

// ---- pre-pass: AiP[b,n,h] = sum_f f[b,n,f]*W1[f,h] + b1[h];  Aj uses W1[64+f]
__global__ __launch_bounds__(256) void prepass_kernel(
    const float* __restrict__ af, const float* __restrict__ W1,
    const float* __restrict__ b1, float* __restrict__ AiP,
    float* __restrict__ Aj)
{
  __shared__ float fl[64];
  const int bn  = blockIdx.x;        // b*64 + n
  const int tid = threadIdx.x;
  const int h    = tid & 127;
  const int half = tid >> 7;         // 0 -> Ai, 1 -> Aj
  if (tid < 64) fl[tid] = af[bn * 128 + tid];   // f slice = first 64 of F=128
  __syncthreads();
  const float* Wp = W1 + (half << 6) * H_SZ + h;
  float acc = 0.f;
#pragma unroll 8
  for (int f = 0; f < 64; ++f) acc = fmaf(fl[f], Wp[f << 7], acc);
  if (half == 0) AiP[bn * H_SZ + h] = acc + b1[h];
  else           Aj [bn * H_SZ + h] = acc;
}

// ---- W2 (128x128 fp32, k-major) -> W2T (n-major) bf16
__global__ __launch_bounds__(256) void w2t_kernel(
    const float* __restrict__ W2, unsigned short* __restrict__ W2T)
{
  int idx = blockIdx.x * 256 + threadIdx.x;    // 0..16383
  int k = idx >> 7, n = idx & 127;
  unsigned u = __float_as_uint(W2[idx]);
  u += 0x7fffu + ((u >> 16) & 1u);
  W2T[n * 128 + k] = (unsigned short)(u >> 16);
}

// ---- softmax over 64 mixing weights (one wave)
__global__ void softmax_kernel(const float* __restrict__ mw,
                               float* __restrict__ outw)
{
  int t = threadIdx.x;               // 0..63
  float v = mw[t];
  float m = v;
  for (int off = 32; off > 0; off >>= 1) m = fmaxf(m, __shfl_xor(m, off));
  float e = expf(v - m);
  float s = e;
  for (int off = 32; off > 0; off >>= 1) s += __shfl_xor(s, off);
  outw[t] = e / s;
}

// ---- main fused kernel: one block = (b, pair of i). 128 rows x 128 cols GEMM
// rows r=0..127 -> i = i0 + r/64, j = r%64;  h1[r,k] = relu(AiP[i,k]+Aj[j,k])
__global__ __launch_bounds__(256) void corr_kernel(
    const float* __restrict__ AiP, const float* __restrict__ Aj,
    const unsigned short* __restrict__ W2T,
    const float* __restrict__ b2, const float* __restrict__ w3,
    const float* __restrict__ b3, float* __restrict__ out)
{
  // 16B-chunk XOR swizzle (chunk e' = e ^ (row&15)) -> bank-even frag reads,
  // no padding, exactly 64 KB total LDS.
  __shared__ __align__(16) unsigned short At[128 * 128];
  __shared__ __align__(16) unsigned short Bt[128 * 128];

  const int tid = threadIdx.x;
  const int b   = blockIdx.x >> 5;
  const int i0  = (blockIdx.x & 31) << 1;

  // stage W2T bf16 -> Bt (swizzled)
  {
    const uint4* src = (const uint4*)W2T;      // 2048 x 16B chunks
#pragma unroll
    for (int it = 0; it < 8; ++it) {
      int idx = (it << 8) + tid;
      int n = idx >> 4, e = idx & 15;
      uint4 v = src[idx];
      *(uint4*)&Bt[(n << 7) + ((e ^ (n & 15)) << 3)] = v;
    }
  }

  // build h1 tile -> At (bf16, swizzled). 16 passes x 8 rows, float4 per thread
  {
    const int kq = tid & 31;                   // float4 column
    const int r8 = tid >> 5;                   // row within pass
    const int e  = kq >> 1, hf = kq & 1;
    const float* AiB = AiP + ((b << 6) + i0) * H_SZ;
    const float* AjB = Aj + (b << 6) * H_SZ;
#pragma unroll
    for (int pass = 0; pass < 16; ++pass) {
      int r = (pass << 3) + r8;
      float4 a4 = ((const float4*)(AiB + ((r >> 6) << 7)))[kq];
      float4 c4 = ((const float4*)(AjB + ((r & 63) << 7)))[kq];
      float x0 = fmaxf(a4.x + c4.x, 0.f);
      float x1 = fmaxf(a4.y + c4.y, 0.f);
      float x2 = fmaxf(a4.z + c4.z, 0.f);
      float x3 = fmaxf(a4.w + c4.w, 0.f);
      uint2 val;
      val.x = pack_bf16x2(x0, x1);
      val.y = pack_bf16x2(x2, x3);
      *(uint2*)&At[(r << 7) + ((e ^ (r & 15)) << 3) + (hf << 2)] = val;
    }
  }

  __syncthreads();

  const int lane = tid & 63;
  const int wave = tid >> 6;
  const int wm = wave >> 1, wn = wave & 1;     // 2x2 waves of 64x64
  const int c = lane & 15, g = lane >> 4;
  const int m0 = wm << 6, n0 = wn << 6;

  f32x4 acc[4][4];
#pragma unroll
  for (int tm = 0; tm < 4; ++tm)
#pragma unroll
    for (int tn = 0; tn < 4; ++tn) acc[tm][tn] = 0.f;

#pragma unroll
  for (int kt = 0; kt < 4; ++kt) {
    const int es = ((kt << 2) + g) ^ c;        // swizzled chunk (row&15 == c)
    bf16x8 av[4], bv[4];
#pragma unroll
    for (int tm = 0; tm < 4; ++tm)
      av[tm] = *(const bf16x8*)&At[((m0 + (tm << 4) + c) << 7) + (es << 3)];
#pragma unroll
    for (int tn = 0; tn < 4; ++tn)
      bv[tn] = *(const bf16x8*)&Bt[((n0 + (tn << 4) + c) << 7) + (es << 3)];
#pragma unroll
    for (int tm = 0; tm < 4; ++tm)
#pragma unroll
      for (int tn = 0; tn < 4; ++tn)
        acc[tm][tn] = __builtin_amdgcn_mfma_f32_16x16x32_bf16(
            av[tm], bv[tn], acc[tm][tn], 0, 0, 0);
  }

  __syncthreads();                 // all frag reads done before aliasing At

  float* corrpart = (float*)At;    // [2][128]

  float b2v[4], w3v[4];
#pragma unroll
  for (int tn = 0; tn < 4; ++tn) {
    int col = n0 + (tn << 4) + c;
    b2v[tn] = b2[col];
    w3v[tn] = w3[col];
  }

  // C/D layout: row = 16*tm + 4*g + p, col = 16*tn + c (m89/m91 verified)
#pragma unroll
  for (int tm = 0; tm < 4; ++tm) {
#pragma unroll
    for (int p = 0; p < 4; ++p) {
      float s = 0.f;
#pragma unroll
      for (int tn = 0; tn < 4; ++tn)
        s += fmaxf(acc[tm][tn][p] + b2v[tn], 0.f) * w3v[tn];
      s += __shfl_xor(s, 1);
      s += __shfl_xor(s, 2);
      s += __shfl_xor(s, 4);
      s += __shfl_xor(s, 8);       // sum over the 16 c-lanes (64-col stripe)
      if (c == 0)
        corrpart[(wn << 7) + m0 + (tm << 4) + (g << 2) + p] = s;
    }
  }

  __syncthreads();

  if (tid < 128) {
    float v = corrpart[tid] + corrpart[128 + tid] + b3[0];
    out[(b << 12) + (i0 << 6) + tid] = 1.f / (1.f + expf(-v));
  }
}

extern "C" void kernel_launch(void* const* d_in, const int* in_sizes, int n_in,
                              void* d_out, int out_size, void* d_ws,
                              size_t ws_size, hipStream_t stream)
{
  const float* af = (const float*)d_in[0];   // (128,64,128)
  const float* W1 = (const float*)d_in[1];   // (128,128)
  const float* b1 = (const float*)d_in[2];   // (128,)
  const float* W2 = (const float*)d_in[3];   // (128,128)
  const float* b2 = (const float*)d_in[4];   // (128,)
  const float* w3 = (const float*)d_in[5];   // (128,)
  const float* b3 = (const float*)d_in[6];   // (1,)
  const float* mw = (const float*)d_in[7];   // (64,)
  float* out = (float*)d_out;                // 524288 corr + 64 weights

  float* AiP = (float*)d_ws;                           // 4 MB
  float* Aj  = AiP + B_SZ * N_SZ * H_SZ;               // 4 MB
  unsigned short* W2T = (unsigned short*)(Aj + B_SZ * N_SZ * H_SZ);  // 32 KB

  prepass_kernel<<<B_SZ * N_SZ, 256, 0, stream>>>(af, W1, b1, AiP, Aj);
  w2t_kernel<<<64, 256, 0, stream>>>(W2, W2T);
  softmax_kernel<<<1, 64, 0, stream>>>(mw, out + B_SZ * N_SZ * N_SZ);
  corr_kernel<<<B_SZ * 32, 256, 0, stream>>>(AiP, Aj, W2T, b2, w3, b3, out);
}

// Round 2
// 125.754 us; speedup vs baseline: 1.1613x; 1.1613x over previous
//
#include <hip/hip_runtime.h>
#include <hip/hip_bf16.h>

// CorrelationNetwork fused kernels for MI355X (gfx950) — round 2.
// R1 post-mortem: corr_kernel was occupancy-bound (19%, 64KB LDS -> 2 blk/CU)
// and 4 launches cost ~84us of helper+overhead. R2: B-frags (W2^T) live in
// registers (no Bt LDS) -> 32KB LDS; 512-thread blocks, 64x32 wave tiles ->
// 16 waves/CU; all setup fused into one kernel -> 2 launches total.

typedef __bf16 bf16x8 __attribute__((ext_vector_type(8)));
typedef float f32x4 __attribute__((ext_vector_type(4)));

#define B_SZ 128
#define N_SZ 64
#define H_SZ 128

__device__ __forceinline__ unsigned pack_bf16x2(float lo, float hi) {
  unsigned a = __float_as_uint(lo);
  unsigned b = __float_as_uint(hi);
  a += 0x7fffu + ((a >> 16) & 1u);   // RNE round to bf16
  b += 0x7fffu + ((b >> 16) & 1u);
  return (a >> 16) | (b & 0xffff0000u);
}

// ---- setup: blocks 0..2047 prepass (4 bn-rows each), 2048..2111 W2->W2T bf16,
//      block 2112 softmax(mixing_weights)
__global__ __launch_bounds__(256) void setup_kernel(
    const float* __restrict__ af, const float* __restrict__ W1,
    const float* __restrict__ b1, const float* __restrict__ W2,
    const float* __restrict__ mw, float* __restrict__ AiP,
    float* __restrict__ Aj, unsigned short* __restrict__ W2T,
    float* __restrict__ outw)
{
  const int blk = blockIdx.x;
  const int tid = threadIdx.x;

  if (blk < 2048) {
    // prepass: AiP[bn,h] = sum_f f[bn,f]*W1[f,h] + b1[h]; Aj via W1[64+f]
    __shared__ float fl[4 * 64];
    const int bn0 = blk << 2;
    // f slice: first 64 of the 128-wide feature dim, 4 rows
    fl[tid] = af[((bn0 + (tid >> 6)) << 7) + (tid & 63)];
    __syncthreads();
    const int h    = tid & 127;
    const int half = tid >> 7;                 // 0 -> Ai, 1 -> Aj
    const float* Wp = W1 + ((half << 6) << 7) + h;
    float acc0 = 0.f, acc1 = 0.f, acc2 = 0.f, acc3 = 0.f;
#pragma unroll
    for (int fq = 0; fq < 16; ++fq) {
      const float w0 = Wp[(fq * 4 + 0) << 7];
      const float w1v = Wp[(fq * 4 + 1) << 7];
      const float w2v = Wp[(fq * 4 + 2) << 7];
      const float w3v = Wp[(fq * 4 + 3) << 7];
      const float4 f0 = *(const float4*)&fl[0 * 64 + (fq << 2)];
      const float4 f1 = *(const float4*)&fl[1 * 64 + (fq << 2)];
      const float4 f2 = *(const float4*)&fl[2 * 64 + (fq << 2)];
      const float4 f3 = *(const float4*)&fl[3 * 64 + (fq << 2)];
      acc0 = fmaf(f0.x, w0, fmaf(f0.y, w1v, fmaf(f0.z, w2v, fmaf(f0.w, w3v, acc0))));
      acc1 = fmaf(f1.x, w0, fmaf(f1.y, w1v, fmaf(f1.z, w2v, fmaf(f1.w, w3v, acc1))));
      acc2 = fmaf(f2.x, w0, fmaf(f2.y, w1v, fmaf(f2.z, w2v, fmaf(f2.w, w3v, acc2))));
      acc3 = fmaf(f3.x, w0, fmaf(f3.y, w1v, fmaf(f3.z, w2v, fmaf(f3.w, w3v, acc3))));
    }
    if (half == 0) {
      const float bb = b1[h];
      AiP[((bn0 + 0) << 7) + h] = acc0 + bb;
      AiP[((bn0 + 1) << 7) + h] = acc1 + bb;
      AiP[((bn0 + 2) << 7) + h] = acc2 + bb;
      AiP[((bn0 + 3) << 7) + h] = acc3 + bb;
    } else {
      Aj[((bn0 + 0) << 7) + h] = acc0;
      Aj[((bn0 + 1) << 7) + h] = acc1;
      Aj[((bn0 + 2) << 7) + h] = acc2;
      Aj[((bn0 + 3) << 7) + h] = acc3;
    }
  } else if (blk < 2112) {
    // W2 (128x128, k-major) -> W2T (n-major) bf16
    int idx = ((blk - 2048) << 8) + tid;       // 0..16383
    int k = idx >> 7, n = idx & 127;
    unsigned u = __float_as_uint(W2[idx]);
    u += 0x7fffu + ((u >> 16) & 1u);
    W2T[(n << 7) + k] = (unsigned short)(u >> 16);
  } else {
    // softmax over 64 mixing weights
    if (tid < 64) {
      float v = mw[tid];
      float m = v;
      for (int off = 32; off > 0; off >>= 1) m = fmaxf(m, __shfl_xor(m, off));
      float e = expf(v - m);
      float s = e;
      for (int off = 32; off > 0; off >>= 1) s += __shfl_xor(s, off);
      outw[tid] = e / s;
    }
  }
}

// ---- main fused kernel: one block = (b, pair of i). 128 rows x 128 cols.
// rows r=0..127 -> i = i0 + r/64, j = r%64;  h1[r,k] = relu(AiP[i,k]+Aj[j,k])
// 512 threads = 8 waves: wm = wave>>2 (64 rows), wn = wave&3 (32 cols).
// W2^T fragments held in registers (same for every block, L1-resident).
__global__ __launch_bounds__(512, 4) void corr_kernel(
    const float* __restrict__ AiP, const float* __restrict__ Aj,
    const unsigned short* __restrict__ W2T,
    const float* __restrict__ b2, const float* __restrict__ w3,
    const float* __restrict__ b3, float* __restrict__ out)
{
  // h1 tile, bf16, 16B-chunk XOR swizzle (chunk e' = e ^ (row&15)): 32 KB
  __shared__ __align__(16) unsigned short At[128 * 128];

  const int tid  = threadIdx.x;
  const int b    = blockIdx.x >> 5;
  const int i0   = (blockIdx.x & 31) << 1;
  const int lane = tid & 63;
  const int wave = tid >> 6;
  const int wm = wave >> 2, wn = wave & 3;
  const int c = lane & 15, g = lane >> 4;
  const int m0 = wm << 6, n0 = wn << 5;

  // B-fragments from global (bf16 W2T, n-major): bfrag[kt][tn] covers
  // cols n0+tn*16+c, k = kt*32 + g*8 .. +7.  8 x 16B loads, L1-hit.
  bf16x8 bfrag[4][2];
#pragma unroll
  for (int kt = 0; kt < 4; ++kt)
#pragma unroll
    for (int tn = 0; tn < 2; ++tn) {
      const int col = n0 + (tn << 4) + c;
      bfrag[kt][tn] =
          *(const bf16x8*)&W2T[(col << 7) + (((kt << 2) + g) << 3)];
    }

  // build h1 tile -> At (bf16, swizzled). 8 passes, float4-pair per thread.
  {
    const int kq = tid & 31;                   // float4 column
    const int rr = tid >> 5;                   // 0..15
    const int e  = kq >> 1, hf = kq & 1;
    const float* AiB = AiP + (((b << 6) + i0) << 7);
    const float* AjB = Aj + ((b << 6) << 7);
#pragma unroll
    for (int pass = 0; pass < 8; ++pass) {
      const int r = (pass << 4) + rr;
      const float4 a4 = ((const float4*)(AiB + ((r >> 6) << 7)))[kq];
      const float4 c4 = ((const float4*)(AjB + ((r & 63) << 7)))[kq];
      uint2 val;
      val.x = pack_bf16x2(fmaxf(a4.x + c4.x, 0.f), fmaxf(a4.y + c4.y, 0.f));
      val.y = pack_bf16x2(fmaxf(a4.z + c4.z, 0.f), fmaxf(a4.w + c4.w, 0.f));
      *(uint2*)&At[(r << 7) + ((e ^ (r & 15)) << 3) + (hf << 2)] = val;
    }
  }

  __syncthreads();

  f32x4 acc[4][2];
#pragma unroll
  for (int tm = 0; tm < 4; ++tm)
#pragma unroll
    for (int tn = 0; tn < 2; ++tn) acc[tm][tn] = 0.f;

#pragma unroll
  for (int kt = 0; kt < 4; ++kt) {
    const int es = ((kt << 2) + g) ^ c;        // swizzled chunk (row low4 == c)
    bf16x8 av[4];
#pragma unroll
    for (int tm = 0; tm < 4; ++tm)
      av[tm] = *(const bf16x8*)&At[((m0 + (tm << 4) + c) << 7) + (es << 3)];
#pragma unroll
    for (int tm = 0; tm < 4; ++tm)
#pragma unroll
      for (int tn = 0; tn < 2; ++tn)
        acc[tm][tn] = __builtin_amdgcn_mfma_f32_16x16x32_bf16(
            av[tm], bfrag[kt][tn], acc[tm][tn], 0, 0, 0);
  }

  __syncthreads();                 // At frag reads done before aliasing

  float* part = (float*)At;        // [128 rows][4 wn]

  float b2v[2], w3v[2];
#pragma unroll
  for (int tn = 0; tn < 2; ++tn) {
    const int col = n0 + (tn << 4) + c;
    b2v[tn] = b2[col];
    w3v[tn] = w3[col];
  }

  // C/D layout: row = 16*tm + 4*g + p, col = 16*tn + c (m89/m91 verified)
#pragma unroll
  for (int tm = 0; tm < 4; ++tm) {
#pragma unroll
    for (int p = 0; p < 4; ++p) {
      float s = fmaxf(acc[tm][0][p] + b2v[0], 0.f) * w3v[0] +
                fmaxf(acc[tm][1][p] + b2v[1], 0.f) * w3v[1];
      s += __shfl_xor(s, 1);
      s += __shfl_xor(s, 2);
      s += __shfl_xor(s, 4);
      s += __shfl_xor(s, 8);       // sum over the 16 c-lanes (32-col stripe)
      if (c == 0)
        part[((m0 + (tm << 4) + (g << 2) + p) << 2) + wn] = s;
    }
  }

  __syncthreads();

  if (tid < 128) {
    const float4 pp = ((const float4*)part)[tid];
    const float v = pp.x + pp.y + pp.z + pp.w + b3[0];
    out[(b << 12) + (i0 << 6) + tid] = 1.f / (1.f + expf(-v));
  }
}

extern "C" void kernel_launch(void* const* d_in, const int* in_sizes, int n_in,
                              void* d_out, int out_size, void* d_ws,
                              size_t ws_size, hipStream_t stream)
{
  const float* af = (const float*)d_in[0];   // (128,64,128)
  const float* W1 = (const float*)d_in[1];   // (128,128)
  const float* b1 = (const float*)d_in[2];   // (128,)
  const float* W2 = (const float*)d_in[3];   // (128,128)
  const float* b2 = (const float*)d_in[4];   // (128,)
  const float* w3 = (const float*)d_in[5];   // (128,)
  const float* b3 = (const float*)d_in[6];   // (1,)
  const float* mw = (const float*)d_in[7];   // (64,)
  float* out = (float*)d_out;                // 524288 corr + 64 weights

  float* AiP = (float*)d_ws;                           // 4 MB
  float* Aj  = AiP + B_SZ * N_SZ * H_SZ;               // 4 MB
  unsigned short* W2T = (unsigned short*)(Aj + B_SZ * N_SZ * H_SZ);  // 32 KB

  setup_kernel<<<2113, 256, 0, stream>>>(af, W1, b1, W2, mw, AiP, Aj, W2T,
                                         out + B_SZ * N_SZ * N_SZ);
  corr_kernel<<<B_SZ * 32, 512, 0, stream>>>(AiP, Aj, W2T, b2, w3, b3, out);
}